// Round 19
// baseline (26.124 us; speedup 1.0000x reference)
//
#include <hip/hip_runtime.h>

// out[b,o] = sum_{i,n} (Ps*tanh(k*(x + Ec*bm)) + bias) * coef
// bm = 1 + c*sg; c = -0.4*sigmoid(-10*(x-prev)); sg = 1/(1+exp2(G*(x+Ec)))
// tanh(a) = 1 - 2*r, r = 1/(1+exp2(kt*inner)); out = base[o] - 2*sum pc*r
//
// R19: amortize n. Thread owns (i, all 8 n): params in 32 VGPRs (4 packed
// n-pairs), ONE b64 {x,c} LDS read per 8 terms (0.75 cyc/term vs R17's 9),
// n-reduction free in-thread. pl stored TRANSPOSED [n][i] so reg-fill b128
// reads are conflict-free (16B lane stride). Zero hw-trans anywhere
// (Schraudolph exp2 clamped vs cvt_i32 overflow; magic-Newton rcp).
// Modeled: VALU 5.3us/SIMD, LDS 0.6us/CU, staging ~2us. 512 blocks (2/CU),
// one 64-row tile, 2 barriers total. If ~24us persists, wall is external.

#define GATE_C 14.426950408889634f   // 10*log2(e)
#define TANH_C 2.8853900817779268f   // 2*log2(e)

typedef float f32x2 __attribute__((ext_vector_type(2)));
typedef float f32x4 __attribute__((ext_vector_type(4)));
typedef int   i32x2 __attribute__((ext_vector_type(2)));

constexpr int B = 512, I = 128, O = 64, NB = 8, BT = 64;

__device__ __forceinline__ f32x2 pk_rcp1(f32x2 d) {   // d>0, ~1.2e-3 rel
  i32x2 yi = (i32x2)(0x7EF127EA) - __builtin_bit_cast(i32x2, d);
  f32x2 y = __builtin_bit_cast(f32x2, yi);
  return y * __builtin_elementwise_fma(-d, y, (f32x2)(2.f));
}
__device__ __forceinline__ f32x2 pk_rcp2(f32x2 d) {   // d>0, ~1.5e-6 rel
  i32x2 yi = (i32x2)(0x7EF127EA) - __builtin_bit_cast(i32x2, d);
  f32x2 y = __builtin_bit_cast(f32x2, yi);
  y = y * __builtin_elementwise_fma(-d, y, (f32x2)(2.f));
  return y * __builtin_elementwise_fma(-d, y, (f32x2)(2.f));
}
// Schraudolph exp2: bitcast((int)(t*2^23 + 1064866805)), +-2.9% rel.
// Main-loop args bounded: |ta|<=~102, |tb|<=~51 -> int < 1.93e9, safe.
__device__ __forceinline__ f32x2 pk_exp2s(f32x2 t) {
  f32x2 r;
  r.x = __int_as_float((int)fmaf(t.x, 8388608.f, 1064866805.f));
  r.y = __int_as_float((int)fmaf(t.y, 8388608.f, 1064866805.f));
  return r;
}
__device__ __forceinline__ float s_exp2s(float t) {
  return __int_as_float((int)fmaf(t, 8388608.f, 1064866805.f));
}
__device__ __forceinline__ float s_rcp1(float d) {
  float y = __int_as_float(0x7EF127EA - __float_as_int(d));
  return y * fmaf(-d, y, 2.f);
}

__global__ __launch_bounds__(1024, 2) void fe_main(
    const float* __restrict__ x, const float* __restrict__ k,
    const float* __restrict__ Ec, const float* __restrict__ Ps,
    const float* __restrict__ bias, const float* __restrict__ coef,
    float* __restrict__ out)
{
  __shared__ f32x4 pl[NB][I];      // TRANSPOSED {ec, G*ec, kt, pc}  16 KB
  __shared__ float2 xc[BT][I];     // {x, ch}                        64 KB
  __shared__ float racc[16][8];    // per-wave, per-row partials
  __shared__ float red[16];        // base[o] partials

  const int tid = threadIdx.x;
  const int o  = blockIdx.y;
  const int b0 = blockIdx.x * BT;
  const int w  = tid >> 6;

  // ---- params for this o (coalesced-ish gather, once) + base[o] ----
  {
    const int i = tid >> 3, n = tid & 7;
    const int g = (i * O + o) * NB + n;
    const float E = Ec[g], K = k[g], P = Ps[g], C = coef[g], Bs = bias[g];
    const float pc = P * C;
    pl[n][i] = (f32x4){E, E * GATE_C, K * TANH_C, pc};
    float pbase = fmaf(Bs, C, pc);
    #pragma unroll
    for (int m = 1; m < 64; m <<= 1) pbase += __shfl_xor(pbase, m);
    if ((tid & 63) == 0) red[w] = pbase;
  }

  // ---- stage {x, ch}: 8 entries/thread, coalesced; zero hw-trans ----
  for (int e = tid; e < BT * I; e += 1024) {
    const int bb = e >> 7, i = e & 127;
    const int bg = b0 + bb;
    const float xv = x[bg * I + i];
    const float pv = (bg == 0) ? 0.f : x[(bg - 1) * I + i];
    const float tg = fminf(GATE_C * (xv - pv), 120.f);   // clamp: cvt safety
    const float ch = -0.4f * s_rcp1(1.f + s_exp2s(tg));
    xc[bb][i] = make_float2(xv, ch);
  }
  __syncthreads();

  // ---- param regs: 8 conflict-free b128 reads, repack to 4 n-pairs ----
  const int i0 = tid & 127, bslot = tid >> 7;
  const f32x4 q0 = pl[0][i0], q1 = pl[1][i0], q2 = pl[2][i0], q3 = pl[3][i0];
  const f32x4 q4 = pl[4][i0], q5 = pl[5][i0], q6 = pl[6][i0], q7 = pl[7][i0];
  const f32x2 ec0 = {q0.x, q1.x}, gg0 = {q0.y, q1.y},
              kt0 = {q0.z, q1.z}, pc0 = {q0.w, q1.w};
  const f32x2 ec1 = {q2.x, q3.x}, gg1 = {q2.y, q3.y},
              kt1 = {q2.z, q3.z}, pc1 = {q2.w, q3.w};
  const f32x2 ec2 = {q4.x, q5.x}, gg2 = {q4.y, q5.y},
              kt2 = {q4.z, q5.z}, pc2 = {q4.w, q5.w};
  const f32x2 ec3 = {q6.x, q7.x}, gg3 = {q6.y, q7.y},
              kt3 = {q6.z, q7.z}, pc3 = {q6.w, q7.w};

  // one n-pair, packed f32x2 (xx, cc splat in scope)
  #define NPAIR(ACC, ECQ, GGQ, KTQ, PCQ) {                                  \
    const f32x2 ta = __builtin_elementwise_fma(xx, (f32x2)(GATE_C), GGQ);   \
    const f32x2 d1 = pk_exp2s(ta) + (f32x2)(1.f);                           \
    const f32x2 sg = pk_rcp1(d1);               /* sigmoid(-10(x+Ec)) */    \
    const f32x2 bm = __builtin_elementwise_fma(cc, sg, (f32x2)(1.f));       \
    const f32x2 inr = __builtin_elementwise_fma(ECQ, bm, xx);               \
    const f32x2 tb = KTQ * inr;                                             \
    const f32x2 d2 = pk_exp2s(tb) + (f32x2)(1.f);                           \
    ACC = __builtin_elementwise_fma(PCQ, pk_rcp2(d2), ACC); }

  // one b-row: 1 conflict-free b64 read covers 8 terms
  #define ROWB(AJ, J) {                                                     \
    const float2 v = xc[bslot * 8 + (J)][i0];                               \
    const f32x2 xx = (f32x2)(v.x);                                          \
    const f32x2 cc = (f32x2)(v.y);                                          \
    NPAIR(AJ, ec0, gg0, kt0, pc0)                                           \
    NPAIR(AJ, ec1, gg1, kt1, pc1)                                           \
    NPAIR(AJ, ec2, gg2, kt2, pc2)                                           \
    NPAIR(AJ, ec3, gg3, kt3, pc3) }

  f32x2 a0 = (f32x2)(0.f), a1 = (f32x2)(0.f), a2 = (f32x2)(0.f),
        a3 = (f32x2)(0.f), a4 = (f32x2)(0.f), a5 = (f32x2)(0.f),
        a6 = (f32x2)(0.f), a7 = (f32x2)(0.f);
  ROWB(a0, 0) ROWB(a1, 1) ROWB(a2, 2) ROWB(a3, 3)
  ROWB(a4, 4) ROWB(a5, 5) ROWB(a6, 6) ROWB(a7, 7)

  // ---- reduce: fold n in-register, butterfly over the 64 lane-i's ----
  #define RED(AJ, J) { float s = AJ.x + AJ.y;                               \
    s += __shfl_xor(s, 1);  s += __shfl_xor(s, 2);  s += __shfl_xor(s, 4);  \
    s += __shfl_xor(s, 8);  s += __shfl_xor(s, 16); s += __shfl_xor(s, 32); \
    if ((tid & 63) == 0) racc[w][J] = s; }
  RED(a0, 0) RED(a1, 1) RED(a2, 2) RED(a3, 3)
  RED(a4, 4) RED(a5, 5) RED(a6, 6) RED(a7, 7)
  __syncthreads();

  // ---- final: 64 threads, one row each; sum the row's 2 waves ----
  if (tid < BT) {
    const int bs = tid >> 3, j = tid & 7;
    const float s = racc[bs * 2][j] + racc[bs * 2 + 1][j];
    float base = 0.f;
    #pragma unroll
    for (int q = 0; q < 16; ++q) base += red[q];
    out[(b0 + tid) * O + o] = fmaf(-2.f, s, base);
  }
  #undef NPAIR
  #undef ROWB
  #undef RED
}

extern "C" void kernel_launch(void* const* d_in, const int* in_sizes, int n_in,
                              void* d_out, int out_size, void* d_ws, size_t ws_size,
                              hipStream_t stream) {
  const float* x    = (const float*)d_in[0];
  const float* k    = (const float*)d_in[1];
  const float* Ec   = (const float*)d_in[2];
  const float* Ps   = (const float*)d_in[3];
  const float* bias = (const float*)d_in[4];
  const float* coef = (const float*)d_in[5];
  float* out = (float*)d_out;

  dim3 grid(B / BT, O);   // (8, 64) = 512 blocks = exactly 2 per CU
  fe_main<<<grid, 1024, 0, stream>>>(x, k, Ec, Ps, bias, coef, out);
}